// Round 3
// baseline (3093.863 us; speedup 1.0000x reference)
//
#include <hip/hip_runtime.h>
#include <hip/hip_bf16.h>

#define B 32
#define H 128
#define L 4096
#define NC 32
#define NL 6
#define T 32          // scan chunk size
#define NCHUNK (L/T)  // 128

typedef __hip_bfloat16 bf16;

__device__ __forceinline__ float b2f(bf16 v) { return __bfloat162float(v); }
__device__ __forceinline__ float bu2f(unsigned int u) {
  union { unsigned int i; float f; } v; v.i = u << 16; return v.f;
}

// h[b,ch,l] = x[b,0,l]*W[0,ch] + x[b,1,l]*W[1,ch] + b[ch]   (fp32 in, bf16 out)
__global__ void encoder_kernel(const float* __restrict__ x, const float* __restrict__ enc_W,
                               const float* __restrict__ enc_b, bf16* __restrict__ h) {
  int blk = blockIdx.x;
  int b = blk >> 7, ch = blk & 127;
  float w0 = enc_W[ch];
  float w1 = enc_W[H + ch];
  float bb = enc_b[ch];
  const float* x0 = x + (size_t)b * 2 * L;
  const float* x1 = x0 + L;
  bf16* out = h + ((size_t)b * H + ch) * L;
  for (int l = threadIdx.x; l < L; l += blockDim.x)
    out[l] = __float2bfloat16(x0[l] * w0 + x1[l] * w1 + bb);
}

// Wt[l][k][o] = out_W[l][o][k], fp32
__global__ void transpose_w_kernel(const float* __restrict__ out_W, float* __restrict__ Wt) {
  int idx = blockIdx.x * 256 + threadIdx.x;
  if (idx >= NL * 2 * H * H) return;
  int l = idx / (2 * H * H);
  int rem = idx % (2 * H * H);
  int o = rem / H;
  int k = rem % H;
  Wt[(size_t)l * 2 * H * H + (size_t)k * (2 * H) + o] = out_W[idx];
}

// S4D conv + skip + GELU for one (b,h) row. Chunked scan, chunk T=32.
__global__ __launch_bounds__(256) void s4d_conv_kernel(
    const bf16* __restrict__ u_g, bf16* __restrict__ y_g,
    const float* __restrict__ log_dt, const float* __restrict__ C_re,
    const float* __restrict__ C_im, const float* __restrict__ log_A_real,
    const float* __restrict__ A_imag, const float* __restrict__ Dp, int layer) {
  __shared__ float u_s[L];                 // 16 KB
  __shared__ float2 S_s[NCHUNK][NC];       // 32 KB: P then (in-place) entering states
  __shared__ float K_s[T];
  __shared__ float2 w_s[NC], cd_s[NC], dta_s[NC];

  int bh = blockIdx.x;              // = b*H + hh
  int hh = bh & 127;
  int tid = threadIdx.x;

  // stage u (bf16 -> fp32 in LDS), 16B vector loads = 8 bf16 each
  const uint4* ug4 = (const uint4*)(u_g + (size_t)bh * L);
  for (int i = tid; i < L / 8; i += 256) {
    uint4 p = ug4[i];
    float* d = u_s + i * 8;
    d[0] = bu2f(p.x & 0xffffu); d[1] = bu2f(p.x >> 16);
    d[2] = bu2f(p.y & 0xffffu); d[3] = bu2f(p.y >> 16);
    d[4] = bu2f(p.z & 0xffffu); d[5] = bu2f(p.z >> 16);
    d[6] = bu2f(p.w & 0xffffu); d[7] = bu2f(p.w >> 16);
  }

  // per-mode discretized params (fp32 inputs)
  if (tid < NC) {
    int n = tid;
    int base = (layer * H + hh) * NC + n;
    float dt = expf(log_dt[layer * H + hh]);
    float Are = -expf(log_A_real[base]);
    float Aim = A_imag[base];
    float dre = dt * Are, dim = dt * Aim;
    float er = expf(dre);
    float wre = er * cosf(dim), wim = er * sinf(dim);
    float emre = wre - 1.f, emim = wim;          // expm1(dtA)
    float cre = C_re[base], cim = C_im[base];
    float nre = cre * emre - cim * emim;
    float nim = cre * emim + cim * emre;
    float den = Are * Are + Aim * Aim;
    cd_s[n] = make_float2((nre * Are + nim * Aim) / den,
                          (nim * Are - nre * Aim) / den);
    w_s[n] = make_float2(wre, wim);
    dta_s[n] = make_float2(dre, dim);
  }
  __syncthreads();

  // Phase P: per-chunk Horner partial sums P[c][n] = sum_t w^(T-1-t) u[c*T+t]
  {
    int n = tid & 31;
    int c0 = tid >> 5;   // 0..7
    float wre = w_s[n].x, wim = w_s[n].y;
    for (int s = 0; s < NCHUNK / 8; ++s) {
      int c = c0 + s * 8;
      const float* uc = u_s + c * T;
      float sre = 0.f, sim = 0.f;
      #pragma unroll
      for (int t = 0; t < T; ++t) {
        float uu = uc[t];
        float nr = wre * sre - wim * sim + uu;
        sim = wre * sim + wim * sre;
        sre = nr;
      }
      S_s[c][n] = make_float2(sre, sim);
    }
  }
  __syncthreads();

  // serial scan over chunks (tid<32) -> S_s[c][n] = state ENTERING chunk c.
  // concurrently compute real kernel K[0..T-1] (tid in [32,64))
  if (tid < NC) {
    int n = tid;
    float2 dta = dta_s[n];
    float er = expf(dta.x * (float)T);
    float wTre = er * cosf(dta.y * (float)T);
    float wTim = er * sinf(dta.y * (float)T);
    float cre = 0.f, cim = 0.f;
    for (int c = 0; c < NCHUNK; ++c) {
      float2 p = S_s[c][n];
      S_s[c][n] = make_float2(cre, cim);
      float nr = wTre * cre - wTim * cim + p.x;
      cim = wTre * cim + wTim * cre + p.y;
      cre = nr;
    }
  } else if (tid < 64) {
    int tau = tid - 32;
    float acc = 0.f;
    #pragma unroll
    for (int n = 0; n < NC; ++n) {
      float2 dta = dta_s[n];
      float2 cd = cd_s[n];
      float e = expf(dta.x * (float)tau);
      float pr = e * cosf(dta.y * (float)tau);
      float pi = e * sinf(dta.y * (float)tau);
      acc += cd.x * pr - cd.y * pi;
    }
    K_s[tau] = 2.f * acc;
  }
  __syncthreads();

  // Phase 2: y[l] = local Toeplitz conv + cross-chunk modal term + D*u, then GELU
  int t = tid & 31;  // within-chunk offset, constant per thread (256 % 32 == 0)
  float wtr[NC], wti[NC];  // cd_n * w^(t+1)
  #pragma unroll
  for (int n = 0; n < NC; ++n) {
    float2 dta = dta_s[n];
    float2 cd = cd_s[n];
    float e = expf(dta.x * (float)(t + 1));
    float pr = e * cosf(dta.y * (float)(t + 1));
    float pi = e * sinf(dta.y * (float)(t + 1));
    wtr[n] = cd.x * pr - cd.y * pi;
    wti[n] = cd.x * pi + cd.y * pr;
  }
  float Dh = Dp[layer * H + hh];
  bf16* yo = y_g + (size_t)bh * L;
  for (int s = 0; s < 16; ++s) {
    int l = s * 256 + tid;
    int c = l >> 5;
    const float* uc = u_s + c * T;
    float acc = 0.f;
    for (int m = 0; m <= t; ++m)
      acc += K_s[t - m] * uc[m];
    float accm = 0.f;
    #pragma unroll
    for (int n = 0; n < NC; ++n) {
      float2 S = S_s[c][n];
      accm += wtr[n] * S.x - wti[n] * S.y;
    }
    float yv = acc + 2.f * accm + u_s[l] * Dh;
    yv = 0.5f * yv * (1.f + erff(yv * 0.70710678118654752f));
    yo[l] = __float2bfloat16(yv);
  }
}

// pointwise conv (2H x H) + GLU + residual + channel LayerNorm, tile of 64 positions
__global__ __launch_bounds__(256) void glu_ln_kernel(
    const bf16* __restrict__ y_g, bf16* __restrict__ h_g,
    const float* __restrict__ Wt,  // [k=128][o=256] for this layer
    const float* __restrict__ out_b, const float* __restrict__ ln_g,
    const float* __restrict__ ln_b, int layer) {
  __shared__ float y_s[H * 64];   // 32 KB: y tile, reused as z tile after GEMM
  __shared__ float mu_s[64], ri_s[64];
  int b = blockIdx.x >> 6;
  int l0 = (blockIdx.x & 63) * 64;
  int tid = threadIdx.x;

  for (int it = tid; it < H * 64; it += 256) {
    int k = it >> 6, j = it & 63;
    y_s[it] = b2f(y_g[((size_t)(b * H + k)) * L + l0 + j]);
  }
  __syncthreads();

  int q = __builtin_amdgcn_readfirstlane(tid >> 6);  // wave id 0..3, scalar
  int j = tid & 63;
  const float* ob = out_b + layer * 2 * H;
  float acc_a[32], acc_g[32];
  #pragma unroll
  for (int i = 0; i < 32; ++i) {
    acc_a[i] = ob[q * 32 + i];
    acc_g[i] = ob[H + q * 32 + i];
  }
  for (int k = 0; k < H; ++k) {
    float yv = y_s[k * 64 + j];
    const float* wr = Wt + (size_t)k * 256 + q * 32;  // wave-uniform -> s_load
    #pragma unroll
    for (int i = 0; i < 32; ++i) {
      acc_a[i] += yv * wr[i];
      acc_g[i] += yv * wr[128 + i];
    }
  }
  float z[32];
  #pragma unroll
  for (int i = 0; i < 32; ++i)
    z[i] = acc_a[i] / (1.f + expf(-acc_g[i]));  // a * sigmoid(g)
  __syncthreads();  // all GEMM reads of y_s complete
  #pragma unroll
  for (int i = 0; i < 32; ++i)
    y_s[(q * 32 + i) * 64 + j] = z[i];
  __syncthreads();

  // residual add (read pre-block h)
  for (int it = tid; it < H * 64; it += 256) {
    int ch = it >> 6, jj = it & 63;
    y_s[it] += b2f(h_g[((size_t)(b * H + ch)) * L + l0 + jj]);
  }
  __syncthreads();

  // LN stats per position
  if (tid < 64) {
    float s1 = 0.f, s2 = 0.f;
    for (int ch = 0; ch < H; ++ch) {
      float v = y_s[ch * 64 + tid];
      s1 += v; s2 += v * v;
    }
    float m = s1 * (1.f / H);
    float var = s2 * (1.f / H) - m * m;
    if (var < 0.f) var = 0.f;
    mu_s[tid] = m;
    ri_s[tid] = rsqrtf(var + 1e-5f);
  }
  __syncthreads();

  const float* lg = ln_g + layer * H;
  const float* lb = ln_b + layer * H;
  for (int it = tid; it < H * 64; it += 256) {
    int ch = it >> 6, jj = it & 63;
    float v = (y_s[it] - mu_s[jj]) * ri_s[jj] * lg[ch] + lb[ch];
    h_g[((size_t)(b * H + ch)) * L + l0 + jj] = __float2bfloat16(v);
  }
}

__global__ __launch_bounds__(256) void pool_kernel(const bf16* __restrict__ h_g,
                                                   float* __restrict__ pooled) {
  int bh = blockIdx.x;
  const bf16* row = h_g + (size_t)bh * L;
  float s = 0.f;
  for (int l = threadIdx.x; l < L; l += 256) s += b2f(row[l]);
  for (int off = 32; off > 0; off >>= 1) s += __shfl_down(s, off);
  __shared__ float wsum[4];
  int lane = threadIdx.x & 63, wv = threadIdx.x >> 6;
  if (lane == 0) wsum[wv] = s;
  __syncthreads();
  if (threadIdx.x == 0)
    pooled[bh] = (wsum[0] + wsum[1] + wsum[2] + wsum[3]) * (1.f / L);
}

__global__ void head_kernel(const float* __restrict__ pooled,
                            const float* __restrict__ head_W,
                            const float* __restrict__ head_b,
                            float* __restrict__ out) {
  int tid = threadIdx.x;
  if (tid >= B * 2) return;
  int b = tid >> 1, o = tid & 1;
  float acc = head_b[o];
  for (int ch = 0; ch < H; ++ch)
    acc += pooled[b * H + ch] * head_W[ch * 2 + o];
  out[tid] = acc;
}

extern "C" void kernel_launch(void* const* d_in, const int* in_sizes, int n_in,
                              void* d_out, int out_size, void* d_ws, size_t ws_size,
                              hipStream_t stream) {
  const float* x          = (const float*)d_in[0];
  const float* enc_W      = (const float*)d_in[1];
  const float* enc_b      = (const float*)d_in[2];
  const float* log_dt     = (const float*)d_in[3];
  const float* C_re       = (const float*)d_in[4];
  const float* C_im       = (const float*)d_in[5];
  const float* log_A_real = (const float*)d_in[6];
  const float* A_imag     = (const float*)d_in[7];
  const float* Dp         = (const float*)d_in[8];
  const float* out_W      = (const float*)d_in[9];
  const float* out_b      = (const float*)d_in[10];
  const float* ln_g       = (const float*)d_in[11];
  const float* ln_b       = (const float*)d_in[12];
  const float* head_W     = (const float*)d_in[13];
  const float* head_b     = (const float*)d_in[14];

  // ws layout (total ~64.8 MB): h bf16 | y bf16 | Wt fp32 | pooled fp32
  bf16* hbuf = (bf16*)d_ws;                          // B*H*L bf16 (32 MB)
  bf16* ybuf = hbuf + (size_t)B * H * L;             // B*H*L bf16 (32 MB)
  float* Wt  = (float*)(ybuf + (size_t)B * H * L);   // NL*2*H*H fp32 (768 KB)
  float* pooled = Wt + (size_t)NL * 2 * H * H;       // B*H fp32

  encoder_kernel<<<B * H, 256, 0, stream>>>(x, enc_W, enc_b, hbuf);
  transpose_w_kernel<<<(NL * 2 * H * H + 255) / 256, 256, 0, stream>>>(out_W, Wt);

  for (int layer = 0; layer < NL; ++layer) {
    s4d_conv_kernel<<<B * H, 256, 0, stream>>>(hbuf, ybuf, log_dt, C_re, C_im,
                                               log_A_real, A_imag, Dp, layer);
    glu_ln_kernel<<<B * (L / 64), 256, 0, stream>>>(
        ybuf, hbuf, Wt + (size_t)layer * 2 * H * H, out_b, ln_g, ln_b, layer);
  }

  pool_kernel<<<B * H, 256, 0, stream>>>(hbuf, pooled);
  head_kernel<<<1, 64, 0, stream>>>(pooled, head_W, head_b, (float*)d_out);
}

// Round 4
// 1359.400 us; speedup vs baseline: 2.2759x; 2.2759x over previous
//
#include <hip/hip_runtime.h>
#include <hip/hip_bf16.h>

#define B 32
#define H 128
#define L 4096
#define NC 32
#define NL 6
#define NCHUNK 128

typedef __hip_bfloat16 bf16;
typedef __attribute__((ext_vector_type(8))) short short8v;   // 8 bf16 (4 VGPR)
typedef __attribute__((ext_vector_type(4))) float floatx4;   // MFMA C/D

__device__ __forceinline__ float b2f(bf16 v) { return __bfloat162float(v); }
__device__ __forceinline__ float bu2f(unsigned int u) {
  union { unsigned int i; float f; } v; v.i = u << 16; return v.f;
}
// float -> bf16 bits, round-to-nearest-even
__device__ __forceinline__ unsigned short f2bs(float f) {
  unsigned u = __float_as_uint(f);
  u = (u + 0x7fffu + ((u >> 16) & 1u)) >> 16;
  return (unsigned short)u;
}

// ---------------- encoder ----------------
__global__ void encoder_kernel(const float* __restrict__ x, const float* __restrict__ enc_W,
                               const float* __restrict__ enc_b, bf16* __restrict__ h) {
  int blk = blockIdx.x;
  int b = blk >> 7, ch = blk & 127;
  float w0 = enc_W[ch];
  float w1 = enc_W[H + ch];
  float bb = enc_b[ch];
  const float* x0 = x + (size_t)b * 2 * L;
  const float* x1 = x0 + L;
  bf16* out = h + ((size_t)b * H + ch) * L;
  for (int l = threadIdx.x; l < L; l += blockDim.x)
    out[l] = __float2bfloat16(x0[l] * w0 + x1[l] * w1 + bb);
}

// Wt[l][k][o] = out_W[l][o][k], fp32
__global__ void transpose_w_kernel(const float* __restrict__ out_W, float* __restrict__ Wt) {
  int idx = blockIdx.x * 256 + threadIdx.x;
  if (idx >= NL * 2 * H * H) return;
  int l = idx / (2 * H * H);
  int rem = idx % (2 * H * H);
  int o = rem / H;
  int k = rem % H;
  Wt[(size_t)l * 2 * H * H + (size_t)k * (2 * H) + o] = out_W[idx];
}

// ---------------- per-(layer,h) B-matrix precompute ----------------
// Global block per h: 12288 bf16 elems (24576 B), hi/lo split pairs:
//   VT_hi [64][40] @0     VT_lo @2560    (VT[n2][t] = Re/Im(w_n^{31-t}), n2=2n/2n+1)
//   KT_hi [32][40] @5120  KT_lo @6400    (KT[t][m] = K[t-m] + D*(t==m), 0 if m>t)
//   WT_hi [32][72] @7680  WT_lo @9984    (WT[t][2n]=2Re(cd w^{t+1}), [2n+1]=-2Im)
__global__ __launch_bounds__(256) void s4d_prep_kernel(
    const float* __restrict__ log_dt, const float* __restrict__ C_re,
    const float* __restrict__ C_im, const float* __restrict__ log_A_real,
    const float* __restrict__ A_imag, const float* __restrict__ Dp,
    unsigned short* __restrict__ Bg, float2* __restrict__ wTg, int layer) {
  __shared__ float2 dta_s[NC], cd_s[NC];
  __shared__ float K_s[32];
  int h = blockIdx.x, tid = threadIdx.x;
  if (tid < NC) {
    int n = tid, base = (layer * H + h) * NC + n;
    float dt = expf(log_dt[layer * H + h]);
    float Are = -expf(log_A_real[base]);
    float Aim = A_imag[base];
    float dre = dt * Are, dim = dt * Aim;
    float er = expf(dre);
    float wre = er * cosf(dim), wim = er * sinf(dim);
    float emre = wre - 1.f, emim = wim;   // expm1(dtA)
    float cre = C_re[base], cim = C_im[base];
    float nre = cre * emre - cim * emim, nim = cre * emim + cim * emre;
    float den = Are * Are + Aim * Aim;
    dta_s[n] = make_float2(dre, dim);
    cd_s[n] = make_float2((nre * Are + nim * Aim) / den, (nim * Are - nre * Aim) / den);
    float e32 = expf(dre * 32.f);
    wTg[h * NC + n] = make_float2(e32 * cosf(dim * 32.f), e32 * sinf(dim * 32.f));
  }
  __syncthreads();
  if (tid < 32) {  // K[tau] = 2 sum_n Re(cd_n w_n^tau)
    float acc = 0.f;
    float tau = (float)tid;
    for (int n = 0; n < NC; ++n) {
      float e = expf(dta_s[n].x * tau);
      float pr = e * cosf(dta_s[n].y * tau), pi = e * sinf(dta_s[n].y * tau);
      acc += cd_s[n].x * pr - cd_s[n].y * pi;
    }
    K_s[tid] = 2.f * acc;
  }
  __syncthreads();
  unsigned short* bb = Bg + (size_t)h * 12288;
  float Dv = Dp[layer * H + h];
  #pragma unroll
  for (int i = 0; i < 8; ++i) {     // VT: 2048 entries
    int idx = tid + i * 256;
    int n2 = idx >> 5, t = idx & 31, n = n2 >> 1;
    float k = (float)(31 - t);
    float e = expf(dta_s[n].x * k);
    float v = (n2 & 1) ? e * sinf(dta_s[n].y * k) : e * cosf(dta_s[n].y * k);
    unsigned short hi = f2bs(v);
    unsigned short lo = f2bs(v - bu2f(hi));
    bb[n2 * 40 + t] = hi;
    bb[2560 + n2 * 40 + t] = lo;
  }
  #pragma unroll
  for (int i = 0; i < 4; ++i) {     // KT: 1024 entries
    int idx = tid + i * 256;
    int t = idx >> 5, m = idx & 31;
    float v = (m > t) ? 0.f : (K_s[t - m] + (m == t ? Dv : 0.f));
    unsigned short hi = f2bs(v);
    unsigned short lo = f2bs(v - bu2f(hi));
    bb[5120 + t * 40 + m] = hi;
    bb[6400 + t * 40 + m] = lo;
  }
  #pragma unroll
  for (int i = 0; i < 8; ++i) {     // WT: 2048 entries
    int idx = tid + i * 256;
    int t = idx >> 6, k = idx & 63, n = k >> 1;
    float tp = (float)(t + 1);
    float e = expf(dta_s[n].x * tp);
    float pr = e * cosf(dta_s[n].y * tp), pi = e * sinf(dta_s[n].y * tp);
    float cwr = cd_s[n].x * pr - cd_s[n].y * pi;
    float cwi = cd_s[n].x * pi + cd_s[n].y * pr;
    float v = (k & 1) ? -2.f * cwi : 2.f * cwr;
    unsigned short hi = f2bs(v);
    unsigned short lo = f2bs(v - bu2f(hi));
    bb[7680 + t * 72 + k] = hi;
    bb[9984 + t * 72 + k] = lo;
  }
}

// ---------------- S4D conv v2: MFMA chunked scan ----------------
// LDS byte map (total 80128 B -> 2 blocks/CU):
//   U    [128][40] bf16 @0       (rows 80 B)
//   S_hi [128][72] bf16 @10240   (rows 144 B; P, then entering states E)
//   S_lo [128][72] bf16 @28672
//   Bmat 24576 B       @47104    (VThi+5120*0, VTlo+5120, KThi+10240, KTlo+12800,
//                                 WThi+15360, WTlo+19968; reused as y_s after MFMAs)
//   wT   32*f2         @71680
//   wTpow[16][32] f2   @71936
//   GE   [8][32] f2    @76032
//   Gt   [8][32] f2    @78080    -> end 80128
__global__ __launch_bounds__(256, 2) void s4d_conv2_kernel(
    const bf16* __restrict__ u_g, bf16* __restrict__ y_g,
    const unsigned short* __restrict__ Bg, const float2* __restrict__ wTg) {
  static __shared__ char __align__(16) sm[80128];
  constexpr int O_U = 0, O_SH = 10240, O_SL = 28672, O_B = 47104;
  constexpr int O_VH = O_B, O_VL = O_B + 5120, O_KH = O_B + 10240, O_KL = O_B + 12800;
  constexpr int O_WH = O_B + 15360, O_WL = O_B + 19968;
  constexpr int O_WT = 71680, O_WP = 71936, O_GE = 76032, O_GT = 78080;

  int tid = threadIdx.x;
  int lane = tid & 63, wv = tid >> 6;
  int r15 = lane & 15, quad = lane >> 4;
  int bh = blockIdx.x, hh = bh & 127;

  // stage U [128][40]
  {
    const uint4* ug = (const uint4*)(u_g + (size_t)bh * L);
    #pragma unroll
    for (int r = 0; r < 2; ++r) {
      int idx = tid + r * 256;
      *(uint4*)(sm + O_U + (idx >> 2) * 80 + (idx & 3) * 16) = ug[idx];
    }
  }
  // stage B matrices (linear copy, 1536 uint4)
  {
    const uint4* bg = (const uint4*)(Bg + (size_t)hh * 12288);
    #pragma unroll
    for (int r = 0; r < 6; ++r) {
      int idx = tid + r * 256;
      *(uint4*)(sm + O_B + idx * 16) = bg[idx];
    }
  }
  if (tid < 32) *(float2*)(sm + O_WT + tid * 8) = wTg[hh * 32 + tid];
  __syncthreads();

  if (tid < 32) {  // wTpow[k][n] = wT^k, k=0..15
    float2 wt = *(const float2*)(sm + O_WT + tid * 8);
    float pr = 1.f, pi = 0.f;
    for (int k = 0; k < 16; ++k) {
      *(float2*)(sm + O_WP + (k * 32 + tid) * 8) = make_float2(pr, pi);
      float nr = pr * wt.x - pi * wt.y;
      pi = pr * wt.y + pi * wt.x;
      pr = nr;
    }
  }

  // ---- phase P: P[c][n2] = sum_t U[c][t] * V[t][n2]
  short8v aU0 = *(const short8v*)(sm + O_U + ((wv * 2 + 0) * 16 + r15) * 80 + quad * 16);
  short8v aU1 = *(const short8v*)(sm + O_U + ((wv * 2 + 1) * 16 + r15) * 80 + quad * 16);
  floatx4 cp[2][4];
  #pragma unroll
  for (int mt = 0; mt < 2; ++mt)
    #pragma unroll
    for (int nt = 0; nt < 4; ++nt) cp[mt][nt] = (floatx4){0.f, 0.f, 0.f, 0.f};
  #pragma unroll
  for (int nt = 0; nt < 4; ++nt) {
    short8v bvh = *(const short8v*)(sm + O_VH + (nt * 16 + r15) * 80 + quad * 16);
    short8v bvl = *(const short8v*)(sm + O_VL + (nt * 16 + r15) * 80 + quad * 16);
    cp[0][nt] = __builtin_amdgcn_mfma_f32_16x16x32_bf16(aU0, bvh, cp[0][nt], 0, 0, 0);
    cp[0][nt] = __builtin_amdgcn_mfma_f32_16x16x32_bf16(aU0, bvl, cp[0][nt], 0, 0, 0);
    cp[1][nt] = __builtin_amdgcn_mfma_f32_16x16x32_bf16(aU1, bvh, cp[1][nt], 0, 0, 0);
    cp[1][nt] = __builtin_amdgcn_mfma_f32_16x16x32_bf16(aU1, bvl, cp[1][nt], 0, 0, 0);
  }
  // P -> S arrays as hi/lo bf16
  #pragma unroll
  for (int mt = 0; mt < 2; ++mt)
    #pragma unroll
    for (int nt = 0; nt < 4; ++nt)
      #pragma unroll
      for (int rg = 0; rg < 4; ++rg) {
        int c = (wv * 2 + mt) * 16 + quad * 4 + rg;
        int n2 = nt * 16 + r15;
        float v = cp[mt][nt][rg];
        unsigned short hi = f2bs(v);
        unsigned short lo = f2bs(v - bu2f(hi));
        *(unsigned short*)(sm + O_SH + c * 144 + n2 * 2) = hi;
        *(unsigned short*)(sm + O_SL + c * 144 + n2 * 2) = lo;
      }
  __syncthreads();

  // ---- scan A: exclusive scan within 16-chunk groups (thread = (group g, mode n))
  {
    int g = tid >> 5, n = tid & 31;
    float2 wt = *(const float2*)(sm + O_WT + n * 8);
    float rr = 0.f, ri = 0.f;
    for (int k = 0; k < 16; ++k) {
      int c = g * 16 + k;
      char* ph = sm + O_SH + c * 144 + n * 4;
      char* pl = sm + O_SL + c * 144 + n * 4;
      unsigned uh = *(unsigned*)ph, ul = *(unsigned*)pl;
      float pre_ = bu2f(uh & 0xffffu) + bu2f(ul & 0xffffu);
      float pim_ = bu2f(uh >> 16) + bu2f(ul >> 16);
      unsigned short hr = f2bs(rr), hjm = f2bs(ri);
      *(unsigned*)ph = ((unsigned)hjm << 16) | hr;
      *(unsigned*)pl = ((unsigned)f2bs(ri - bu2f(hjm)) << 16) | f2bs(rr - bu2f(hr));
      float nr = wt.x * rr - wt.y * ri + pre_;
      ri = wt.x * ri + wt.y * rr + pim_;
      rr = nr;
    }
    *(float2*)(sm + O_GT + (g * 32 + n) * 8) = make_float2(rr, ri);
  }
  __syncthreads();
  // ---- scan B: serial over 8 groups with multiplier wT^16
  if (tid < 32) {
    float2 wt = *(const float2*)(sm + O_WT + tid * 8);
    float2 p15 = *(const float2*)(sm + O_WP + (15 * 32 + tid) * 8);
    float w16r = p15.x * wt.x - p15.y * wt.y;
    float w16i = p15.x * wt.y + p15.y * wt.x;
    float rr = 0.f, ri = 0.f;
    for (int g = 0; g < 8; ++g) {
      *(float2*)(sm + O_GE + (g * 32 + tid) * 8) = make_float2(rr, ri);
      float2 gt = *(const float2*)(sm + O_GT + (g * 32 + tid) * 8);
      float nr = w16r * rr - w16i * ri + gt.x;
      ri = w16r * ri + w16i * rr + gt.y;
      rr = nr;
    }
  }
  __syncthreads();
  // ---- fixup: E[c] += wT^{c&15} * GE[g]
  {
    int g = tid >> 5, n = tid & 31;
    float2 ge = *(const float2*)(sm + O_GE + (g * 32 + n) * 8);
    for (int k = 0; k < 16; ++k) {
      int c = g * 16 + k;
      float2 wp = *(const float2*)(sm + O_WP + (k * 32 + n) * 8);
      float ar = wp.x * ge.x - wp.y * ge.y;
      float ai = wp.x * ge.y + wp.y * ge.x;
      char* ph = sm + O_SH + c * 144 + n * 4;
      char* pl = sm + O_SL + c * 144 + n * 4;
      unsigned uh = *(unsigned*)ph, ul = *(unsigned*)pl;
      float er = bu2f(uh & 0xffffu) + bu2f(ul & 0xffffu) + ar;
      float ei = bu2f(uh >> 16) + bu2f(ul >> 16) + ai;
      unsigned short hr = f2bs(er), him = f2bs(ei);
      *(unsigned*)ph = ((unsigned)him << 16) | hr;
      *(unsigned*)pl = ((unsigned)f2bs(ei - bu2f(him)) << 16) | f2bs(er - bu2f(hr));
    }
  }
  __syncthreads();

  // ---- Toeplitz + modal MFMAs into one accumulator
  floatx4 acc[2][2];
  #pragma unroll
  for (int mt = 0; mt < 2; ++mt)
    #pragma unroll
    for (int nt = 0; nt < 2; ++nt) acc[mt][nt] = (floatx4){0.f, 0.f, 0.f, 0.f};
  #pragma unroll
  for (int nt = 0; nt < 2; ++nt) {
    short8v kh = *(const short8v*)(sm + O_KH + (nt * 16 + r15) * 80 + quad * 16);
    short8v kl = *(const short8v*)(sm + O_KL + (nt * 16 + r15) * 80 + quad * 16);
    acc[0][nt] = __builtin_amdgcn_mfma_f32_16x16x32_bf16(aU0, kh, acc[0][nt], 0, 0, 0);
    acc[0][nt] = __builtin_amdgcn_mfma_f32_16x16x32_bf16(aU0, kl, acc[0][nt], 0, 0, 0);
    acc[1][nt] = __builtin_amdgcn_mfma_f32_16x16x32_bf16(aU1, kh, acc[1][nt], 0, 0, 0);
    acc[1][nt] = __builtin_amdgcn_mfma_f32_16x16x32_bf16(aU1, kl, acc[1][nt], 0, 0, 0);
  }
  #pragma unroll
  for (int ks = 0; ks < 2; ++ks) {
    short8v sh0 = *(const short8v*)(sm + O_SH + ((wv * 2 + 0) * 16 + r15) * 144 + ks * 64 + quad * 16);
    short8v sh1 = *(const short8v*)(sm + O_SH + ((wv * 2 + 1) * 16 + r15) * 144 + ks * 64 + quad * 16);
    short8v sl0 = *(const short8v*)(sm + O_SL + ((wv * 2 + 0) * 16 + r15) * 144 + ks * 64 + quad * 16);
    short8v sl1 = *(const short8v*)(sm + O_SL + ((wv * 2 + 1) * 16 + r15) * 144 + ks * 64 + quad * 16);
    #pragma unroll
    for (int nt = 0; nt < 2; ++nt) {
      short8v wh = *(const short8v*)(sm + O_WH + (nt * 16 + r15) * 144 + ks * 64 + quad * 16);
      short8v wl = *(const short8v*)(sm + O_WL + (nt * 16 + r15) * 144 + ks * 64 + quad * 16);
      acc[0][nt] = __builtin_amdgcn_mfma_f32_16x16x32_bf16(sh0, wh, acc[0][nt], 0, 0, 0);
      acc[0][nt] = __builtin_amdgcn_mfma_f32_16x16x32_bf16(sh0, wl, acc[0][nt], 0, 0, 0);
      acc[0][nt] = __builtin_amdgcn_mfma_f32_16x16x32_bf16(sl0, wh, acc[0][nt], 0, 0, 0);
      acc[1][nt] = __builtin_amdgcn_mfma_f32_16x16x32_bf16(sh1, wh, acc[1][nt], 0, 0, 0);
      acc[1][nt] = __builtin_amdgcn_mfma_f32_16x16x32_bf16(sh1, wl, acc[1][nt], 0, 0, 0);
      acc[1][nt] = __builtin_amdgcn_mfma_f32_16x16x32_bf16(sl1, wh, acc[1][nt], 0, 0, 0);
    }
  }
  __syncthreads();  // all MFMA LDS reads done; reuse Bmat region as y staging

  // ---- epilogue: GELU, stage y, coalesced store
  #pragma unroll
  for (int mt = 0; mt < 2; ++mt)
    #pragma unroll
    for (int nt = 0; nt < 2; ++nt)
      #pragma unroll
      for (int rg = 0; rg < 4; ++rg) {
        int c = (wv * 2 + mt) * 16 + quad * 4 + rg;
        int t = nt * 16 + r15;
        float v = acc[mt][nt][rg];
        v = 0.5f * v * (1.f + erff(v * 0.70710678118654752f));
        *(unsigned short*)(sm + O_B + (c * 32 + t) * 2) = f2bs(v);
      }
  __syncthreads();
  {
    uint4* yo = (uint4*)(y_g + (size_t)bh * L);
    #pragma unroll
    for (int r = 0; r < 2; ++r) {
      int idx = tid + r * 256;
      yo[idx] = *(const uint4*)(sm + O_B + idx * 16);
    }
  }
}

// ---------------- pointwise conv + GLU + residual + LN ----------------
__global__ __launch_bounds__(256) void glu_ln_kernel(
    const bf16* __restrict__ y_g, bf16* __restrict__ h_g,
    const float* __restrict__ Wt,  // [k=128][o=256] for this layer
    const float* __restrict__ out_b, const float* __restrict__ ln_g,
    const float* __restrict__ ln_b, int layer) {
  __shared__ float y_s[H * 64];
  __shared__ float mu_s[64], ri_s[64];
  int b = blockIdx.x >> 6;
  int l0 = (blockIdx.x & 63) * 64;
  int tid = threadIdx.x;

  for (int it = tid; it < H * 64; it += 256) {
    int k = it >> 6, j = it & 63;
    y_s[it] = b2f(y_g[((size_t)(b * H + k)) * L + l0 + j]);
  }
  __syncthreads();

  int q = __builtin_amdgcn_readfirstlane(tid >> 6);
  int j = tid & 63;
  const float* ob = out_b + layer * 2 * H;
  float acc_a[32], acc_g[32];
  #pragma unroll
  for (int i = 0; i < 32; ++i) {
    acc_a[i] = ob[q * 32 + i];
    acc_g[i] = ob[H + q * 32 + i];
  }
  for (int k = 0; k < H; ++k) {
    float yv = y_s[k * 64 + j];
    const float* wr = Wt + (size_t)k * 256 + q * 32;
    #pragma unroll
    for (int i = 0; i < 32; ++i) {
      acc_a[i] += yv * wr[i];
      acc_g[i] += yv * wr[128 + i];
    }
  }
  float z[32];
  #pragma unroll
  for (int i = 0; i < 32; ++i)
    z[i] = acc_a[i] / (1.f + expf(-acc_g[i]));
  __syncthreads();
  #pragma unroll
  for (int i = 0; i < 32; ++i)
    y_s[(q * 32 + i) * 64 + j] = z[i];
  __syncthreads();

  for (int it = tid; it < H * 64; it += 256) {
    int ch = it >> 6, jj = it & 63;
    y_s[it] += b2f(h_g[((size_t)(b * H + ch)) * L + l0 + jj]);
  }
  __syncthreads();

  if (tid < 64) {
    float s1 = 0.f, s2 = 0.f;
    for (int ch = 0; ch < H; ++ch) {
      float v = y_s[ch * 64 + tid];
      s1 += v; s2 += v * v;
    }
    float m = s1 * (1.f / H);
    float var = s2 * (1.f / H) - m * m;
    if (var < 0.f) var = 0.f;
    mu_s[tid] = m;
    ri_s[tid] = rsqrtf(var + 1e-5f);
  }
  __syncthreads();

  const float* lg = ln_g + layer * H;
  const float* lb = ln_b + layer * H;
  for (int it = tid; it < H * 64; it += 256) {
    int ch = it >> 6, jj = it & 63;
    float v = (y_s[it] - mu_s[jj]) * ri_s[jj] * lg[ch] + lb[ch];
    h_g[((size_t)(b * H + ch)) * L + l0 + jj] = __float2bfloat16(v);
  }
}

__global__ __launch_bounds__(256) void pool_kernel(const bf16* __restrict__ h_g,
                                                   float* __restrict__ pooled) {
  int bh = blockIdx.x;
  const bf16* row = h_g + (size_t)bh * L;
  float s = 0.f;
  for (int l = threadIdx.x; l < L; l += 256) s += b2f(row[l]);
  for (int off = 32; off > 0; off >>= 1) s += __shfl_down(s, off);
  __shared__ float wsum[4];
  int lane = threadIdx.x & 63, wv = threadIdx.x >> 6;
  if (lane == 0) wsum[wv] = s;
  __syncthreads();
  if (threadIdx.x == 0)
    pooled[bh] = (wsum[0] + wsum[1] + wsum[2] + wsum[3]) * (1.f / L);
}

__global__ void head_kernel(const float* __restrict__ pooled,
                            const float* __restrict__ head_W,
                            const float* __restrict__ head_b,
                            float* __restrict__ out) {
  int tid = threadIdx.x;
  if (tid >= B * 2) return;
  int b = tid >> 1, o = tid & 1;
  float acc = head_b[o];
  for (int ch = 0; ch < H; ++ch)
    acc += pooled[b * H + ch] * head_W[ch * 2 + o];
  out[tid] = acc;
}

extern "C" void kernel_launch(void* const* d_in, const int* in_sizes, int n_in,
                              void* d_out, int out_size, void* d_ws, size_t ws_size,
                              hipStream_t stream) {
  const float* x          = (const float*)d_in[0];
  const float* enc_W      = (const float*)d_in[1];
  const float* enc_b      = (const float*)d_in[2];
  const float* log_dt     = (const float*)d_in[3];
  const float* C_re       = (const float*)d_in[4];
  const float* C_im       = (const float*)d_in[5];
  const float* log_A_real = (const float*)d_in[6];
  const float* A_imag     = (const float*)d_in[7];
  const float* Dp         = (const float*)d_in[8];
  const float* out_W      = (const float*)d_in[9];
  const float* out_b      = (const float*)d_in[10];
  const float* ln_g       = (const float*)d_in[11];
  const float* ln_b       = (const float*)d_in[12];
  const float* head_W     = (const float*)d_in[13];
  const float* head_b     = (const float*)d_in[14];

  // ws: hbuf bf16 32MB | ybuf bf16 32MB | Wt fp32 768KB | pooled 16KB | Bg 3MB | wTg 32KB
  bf16* hbuf = (bf16*)d_ws;
  bf16* ybuf = hbuf + (size_t)B * H * L;
  float* Wt  = (float*)(ybuf + (size_t)B * H * L);
  float* pooled = Wt + (size_t)NL * 2 * H * H;
  unsigned short* Bg = (unsigned short*)(pooled + B * H);
  float2* wTg = (float2*)(Bg + (size_t)12288 * H);

  encoder_kernel<<<B * H, 256, 0, stream>>>(x, enc_W, enc_b, hbuf);
  transpose_w_kernel<<<(NL * 2 * H * H + 255) / 256, 256, 0, stream>>>(out_W, Wt);

  for (int layer = 0; layer < NL; ++layer) {
    s4d_prep_kernel<<<H, 256, 0, stream>>>(log_dt, C_re, C_im, log_A_real,
                                           A_imag, Dp, Bg, wTg, layer);
    s4d_conv2_kernel<<<B * H, 256, 0, stream>>>(hbuf, ybuf, Bg, wTg);
    glu_ln_kernel<<<B * (L / 64), 256, 0, stream>>>(
        ybuf, hbuf, Wt + (size_t)layer * 2 * H * H, out_b, ln_g, ln_b, layer);
  }

  pool_kernel<<<B * H, 256, 0, stream>>>(hbuf, pooled);
  head_kernel<<<1, 64, 0, stream>>>(pooled, head_W, head_b, (float*)d_out);
}